// Round 17
// baseline (319.963 us; speedup 1.0000x reference)
//
#include <hip/hip_runtime.h>
#include <math.h>

#define DD 256
#define NH 8
#define HD 32
#define NL 4
#define NP 4
#define DFF 1024
#define BB 16
#define LQ 900
#define S_TOT 13294

#define M1   (BB * LQ)        // 14400
#define MP1  14464            // padded to 128
#define MV   (BB * S_TOT)     // 212704
#define MPV  212736           // padded to 128

typedef unsigned short u16;
typedef unsigned int   u32;
typedef __attribute__((ext_vector_type(8))) short s8v;   // 8 bf16 (4 VGPR)
typedef __attribute__((ext_vector_type(4))) float f32x4; // 4 f32 acc

// hard-coded level geometry (fixed constants of this problem)
__constant__ int c_H[NL]    = {100, 50, 25, 13};
__constant__ int c_W[NL]    = {100, 50, 25, 13};
__constant__ int c_base[NL] = {0, 10000, 12500, 13125};

__device__ __forceinline__ float b2f(u16 u) {
    return __uint_as_float(((u32)u) << 16);
}
__device__ __forceinline__ u16 f2b(float f) {
    u32 x = __float_as_uint(f);
    u32 r = x + 0x7fffu + ((x >> 16) & 1u);   // RNE
    return (u16)(r >> 16);
}
__device__ __forceinline__ u32 pk2(float a, float b) {
    return (u32)f2b(a) | ((u32)f2b(b) << 16);
}
// async global->LDS, 16B per lane; ldsbase must be wave-uniform
__device__ __forceinline__ void gload16(const u16* g, u16* ldsbase) {
    __builtin_amdgcn_global_load_lds(
        (const __attribute__((address_space(1))) unsigned int*)(const void*)g,
        (__attribute__((address_space(3))) unsigned int*)(void*)ldsbase,
        16, 0, 0);
}
// bijective XCD-aware swizzle (m204 form)
__device__ __forceinline__ int2 xcd_swizzle()
{
    int nwg  = gridDim.x * gridDim.y;
    int orig = blockIdx.y * gridDim.x + blockIdx.x;
    int q = nwg >> 3, r = nwg & 7;
    int xcd = orig & 7, pos = orig >> 3;
    int wg = (xcd < r ? xcd * (q + 1) : r * (q + 1) + (xcd - r) * q) + pos;
    int2 res;
    res.x = wg % gridDim.x;
    res.y = wg / gridDim.x;
    return res;
}

// WTS layout offsets (u16 units)
#define OFF_QK   0
#define OFF_V    131072
#define OFF_O    196608
#define OFF_VAL  262144
#define OFF_OUT  327680
#define OFF_OA   393216
#define OFF_F1   491520
#define OFF_F2   753664
#define WTS_TOT  1015808

// ------------------------------------------------ consolidated weight prep
__global__ __launch_bounds__(256)
void prep_kernel(const float* __restrict__ Wq, const float* __restrict__ Wk,
                 const float* __restrict__ Wv, const float* __restrict__ Wo,
                 const float* __restrict__ Wval, const float* __restrict__ Wout,
                 const float* __restrict__ Woff, const float* __restrict__ Waw,
                 const float* __restrict__ W1f, const float* __restrict__ W2f,
                 const float* __restrict__ pbq, const float* __restrict__ pbk,
                 const float* __restrict__ boff, const float* __restrict__ baw,
                 u16* __restrict__ WTS, float* __restrict__ bqk, float* __restrict__ boa)
{
    int t = blockIdx.x;
    if (t >= 992) {
        if (t == 992) {
            for (int i = threadIdx.x; i < 512; i += 256)
                bqk[i] = (i < 256) ? pbq[i] : pbk[i - 256];
        } else {
            for (int i = threadIdx.x; i < 384; i += 256)
                boa[i] = (i < 256) ? boff[i] : baw[i - 256];
        }
        return;
    }
    const float* src; u16* dst; int K, N, tt;
    if (t < 448) {
        int wsel = t >> 6; tt = t & 63;
        const float* srcs[7] = {Wq, Wk, Wv, Wo, Wval, Wout, Woff};
        const int   offs[7]  = {OFF_QK, OFF_QK + 65536, OFF_V, OFF_O, OFF_VAL, OFF_OUT, OFF_OA};
        src = srcs[wsel]; dst = WTS + offs[wsel]; K = 256; N = 256;
    } else if (t < 480) {
        tt = t - 448; src = Waw; dst = WTS + OFF_OA + 65536; K = 256; N = 128;
    } else if (t < 736) {
        tt = t - 480; src = W1f; dst = WTS + OFF_F1; K = 256; N = 1024;
    } else {
        tt = t - 736; src = W2f; dst = WTS + OFF_F2; K = 1024; N = 256;
    }
    int nt = N / 32;
    int n0 = (tt % nt) * 32, k0 = (tt / nt) * 32;

    __shared__ float tb[32][33];
    int tx = threadIdx.x & 31, ty = threadIdx.x >> 5;
    #pragma unroll
    for (int i = 0; i < 4; ++i) {
        int k = ty + i * 8;
        tb[k][tx] = src[(size_t)(k0 + k) * N + n0 + tx];
    }
    __syncthreads();
    #pragma unroll
    for (int i = 0; i < 4; ++i) {
        int n = ty + i * 8;
        dst[(size_t)(n0 + n) * K + k0 + tx] = f2b(tb[tx][n]);
    }
}

// ------------------------------------------------ dual activation cvt
__global__ __launch_bounds__(256)
void acvt2_kernel(const float* __restrict__ tgt, const float* __restrict__ qpos,
                  u16* __restrict__ B0, u16* __restrict__ B1)
{
    int i8 = blockIdx.x * 256 + threadIdx.x;
    int row = i8 >> 5;
    uint4 o0, o1;
    if (row < M1) {
        const float4* tp = (const float4*)(tgt + (size_t)i8 * 8);
        const float4* pp = (const float4*)(qpos + (size_t)i8 * 8);
        float4 t0 = tp[0], t1 = tp[1], p0 = pp[0], p1 = pp[1];
        o1.x = pk2(t0.x, t0.y); o1.y = pk2(t0.z, t0.w);
        o1.z = pk2(t1.x, t1.y); o1.w = pk2(t1.z, t1.w);
        o0.x = pk2(t0.x + p0.x, t0.y + p0.y); o0.y = pk2(t0.z + p0.z, t0.w + p0.w);
        o0.z = pk2(t1.x + p1.x, t1.y + p1.y); o0.w = pk2(t1.z + p1.z, t1.w + p1.w);
    } else {
        o0.x = o0.y = o0.z = o0.w = 0;
        o1 = o0;
    }
    ((uint4*)B0)[i8] = o0;
    ((uint4*)B1)[i8] = o1;
}

// ------------------------------------------------ bf16 MFMA GEMM, 2-phase dbuf + XCD swizzle
template<int BNT, int OUTBF, int RELU>
__global__ __launch_bounds__(256)
void mgemm(const u16* __restrict__ A, const u16* __restrict__ Bt,
           const float* __restrict__ bias, void* __restrict__ Cv,
           int K, int N, int Mreal)
{
    constexpr int MF = (BNT == 128) ? 4 : 2;
    __shared__ u16 Asu[2][128 * 32];
    __shared__ u16 Bsu[2][BNT * 32];

    int2 sw = xcd_swizzle();
    int tid = threadIdx.x;
    int w = tid >> 6, l = tid & 63;
    int mbase = (BNT == 128) ? (w >> 1) * 64 : w * 32;
    int nbase = (BNT == 128) ? (w & 1) * 64 : 0;
    long m0 = (long)sw.y * 128;
    int n0 = sw.x * BNT;

    f32x4 acc[MF][4];
    #pragma unroll
    for (int i = 0; i < MF; ++i)
        #pragma unroll
        for (int j = 0; j < 4; ++j) {
            acc[i][j][0] = 0.f; acc[i][j][1] = 0.f;
            acc[i][j][2] = 0.f; acc[i][j][3] = 0.f;
        }

    int lr = l & 15, lk = (l >> 4) * 8;
    int srow = l >> 2;
    int scol = (l & 3) * 8;

    auto stage = [&](int buf, int k0) {
        if (BNT == 128) {
            #pragma unroll
            for (int j = 0; j < 2; ++j) {
                int row = w * 32 + j * 16;
                gload16(Bt + (size_t)(n0 + row + srow) * K + k0 + scol, &Bsu[buf][row * 32]);
            }
        } else {
            int row = w * 16;
            gload16(Bt + (size_t)(n0 + row + srow) * K + k0 + scol, &Bsu[buf][row * 32]);
        }
        #pragma unroll
        for (int j = 0; j < 2; ++j) {
            int row = w * 32 + j * 16;
            gload16(A + (m0 + row + srow) * (long)K + k0 + scol, &Asu[buf][row * 32]);
        }
    };

    int nsteps = K >> 5;
    stage(0, 0);
    __syncthreads();

    int cur = 0;
    for (int s = 0; s < nsteps; ++s) {
        if (s + 1 < nsteps) stage(cur ^ 1, (s + 1) * 32);
        s8v af[MF], bf[4];
        #pragma unroll
        for (int mi = 0; mi < MF; ++mi)
            af[mi] = *(const s8v*)(Asu[cur] + (mbase + mi * 16 + lr) * 32 + lk);
        #pragma unroll
        for (int nj = 0; nj < 4; ++nj)
            bf[nj] = *(const s8v*)(Bsu[cur] + (nbase + nj * 16 + lr) * 32 + lk);
        #pragma unroll
        for (int mi = 0; mi < MF; ++mi)
            #pragma unroll
            for (int nj = 0; nj < 4; ++nj)
                acc[mi][nj] = __builtin_amdgcn_mfma_f32_16x16x32_bf16(
                    af[mi], bf[nj], acc[mi][nj], 0, 0, 0);
        __syncthreads();
        cur ^= 1;
    }

    int lq = l >> 4;
    #pragma unroll
    for (int nj = 0; nj < 4; ++nj) {
        int col = n0 + nbase + nj * 16 + lr;
        float bv = bias[col];
        #pragma unroll
        for (int mi = 0; mi < MF; ++mi) {
            #pragma unroll
            for (int r = 0; r < 4; ++r) {
                long row = m0 + mbase + mi * 16 + lq * 4 + r;
                float v = acc[mi][nj][r] + bv;
                if (RELU) v = fmaxf(v, 0.f);
                if (OUTBF) ((u16*)Cv)[row * N + col] = f2b(v);
                else       ((float*)Cv)[row * N + col] = v;
            }
        }
    }
}

// ------------------------------------------------ value GEMM: 64x128 tile + XCD swizzle
__global__ __launch_bounds__(256)
void vgemm(const float* __restrict__ A, const u16* __restrict__ Bt,
           const float* __restrict__ bias, u16* __restrict__ C, int Mreal)
{
    const int K = 256, N = 256;
    __shared__ u16 Asu[64 * 32];
    __shared__ u16 Bsu[128 * 32];

    int2 sw = xcd_swizzle();
    int tid = threadIdx.x;
    int w = tid >> 6, l = tid & 63;
    int wr = w >> 1, wc = w & 1;
    long m0 = (long)sw.y * 64;
    int n0 = sw.x * 128;

    f32x4 acc[2][4];
    #pragma unroll
    for (int i = 0; i < 2; ++i)
        #pragma unroll
        for (int j = 0; j < 4; ++j) {
            acc[i][j][0] = 0.f; acc[i][j][1] = 0.f;
            acc[i][j][2] = 0.f; acc[i][j][3] = 0.f;
        }

    int lr = l & 15, lk = (l >> 4) * 8;
    int srow = l >> 2, scol = (l & 3) * 8;

    for (int k0 = 0; k0 < K; k0 += 32) {
        #pragma unroll
        for (int j = 0; j < 2; ++j) {
            int row = w * 32 + j * 16;
            gload16(Bt + (size_t)(n0 + row + srow) * K + k0 + scol, &Bsu[row * 32]);
        }
        int c = tid;
        #pragma unroll
        for (int it = 0; it < 2; ++it) {
            int row = c >> 3, col = (c & 7) * 4;
            long gr = m0 + row;
            if (gr >= Mreal) gr = Mreal - 1;
            float4 v = *(const float4*)(A + gr * K + k0 + col);
            ushort4 o;
            o.x = f2b(v.x); o.y = f2b(v.y); o.z = f2b(v.z); o.w = f2b(v.w);
            ((ushort4*)Asu)[c] = o;
            c += 256;
        }
        __syncthreads();
        s8v af[2], bf[4];
        #pragma unroll
        for (int mi = 0; mi < 2; ++mi)
            af[mi] = *(const s8v*)(Asu + (wr * 32 + mi * 16 + lr) * 32 + lk);
        #pragma unroll
        for (int nj = 0; nj < 4; ++nj)
            bf[nj] = *(const s8v*)(Bsu + (wc * 64 + nj * 16 + lr) * 32 + lk);
        #pragma unroll
        for (int mi = 0; mi < 2; ++mi)
            #pragma unroll
            for (int nj = 0; nj < 4; ++nj)
                acc[mi][nj] = __builtin_amdgcn_mfma_f32_16x16x32_bf16(
                    af[mi], bf[nj], acc[mi][nj], 0, 0, 0);
        __syncthreads();
    }

    int lq = l >> 4;
    #pragma unroll
    for (int nj = 0; nj < 4; ++nj) {
        int col = n0 + wc * 64 + nj * 16 + lr;
        float bv = bias[col];
        #pragma unroll
        for (int mi = 0; mi < 2; ++mi) {
            #pragma unroll
            for (int r = 0; r < 4; ++r) {
                long row = m0 + wr * 32 + mi * 16 + lq * 4 + r;
                C[row * N + col] = f2b(acc[mi][nj][r] + bv);
            }
        }
    }
}

// ------------------------------------------------ MFMA flash self-attention, KT=64
#define QT 64
#define KT2 64
#define KSP 48
#define VSP 40
#define PSP 72
__global__ __launch_bounds__(256)
void mattn(const u16* __restrict__ qk, const u16* __restrict__ vh,
           u16* __restrict__ sa)
{
    __shared__ u16 Ks[KT2][KSP];
    __shared__ u32 Vt32[32][VSP];
    __shared__ u16 Ps[4][16][PSP];

    int tid = threadIdx.x;
    int w = tid >> 6, l = tid & 63;
    int lr = l & 15, hi = l >> 4;
    int b = blockIdx.x >> 3, h = blockIdx.x & 7;
    int q0 = blockIdx.y * QT + w * 16;

    s8v qf;
    {
        s8v raw = *(const s8v*)(qk + ((size_t)(b * LQ + q0 + lr) * 512) + h * HD + hi * 8);
        #pragma unroll
        for (int j = 0; j < 8; ++j)
            raw[j] = (short)f2b(b2f((u16)raw[j]) * 0.17677669529663687f);
        qf = raw;
    }

    f32x4 o0 = {0.f,0.f,0.f,0.f}, o1 = {0.f,0.f,0.f,0.f};
    float lrun[4] = {0.f,0.f,0.f,0.f};

    const u16* kbase = qk + (size_t)b * LQ * 512 + 256 + h * HD;
    const u16* vbase = vh + (size_t)b * LQ * 256 + h * HD;

    int krow = tid >> 2, kc8 = (tid & 3) * 8;
    int k2 = tid & 31, d0 = (tid >> 5) * 4;

    for (int kb = 0; kb < LQ; kb += KT2) {
        int gk = kb + krow;        if (gk >= LQ) gk = LQ - 1;
        int gv0 = kb + 2 * k2;     if (gv0 >= LQ) gv0 = LQ - 1;
        int gv1 = kb + 2 * k2 + 1; if (gv1 >= LQ) gv1 = LQ - 1;
        uint4 kv = *(const uint4*)(kbase + (size_t)gk * 512 + kc8);
        uint2 va = *(const uint2*)(vbase + (size_t)gv0 * 256 + d0);
        uint2 vb = *(const uint2*)(vbase + (size_t)gv1 * 256 + d0);
        __syncthreads();
        *(uint4*)(&Ks[krow][kc8]) = kv;
        Vt32[d0 + 0][k2] = (va.x & 0xffffu)      | (vb.x << 16);
        Vt32[d0 + 1][k2] = (va.x >> 16)          | (vb.x & 0xffff0000u);
        Vt32[d0 + 2][k2] = (va.y & 0xffffu)      | (vb.y << 16);
        Vt32[d0 + 3][k2] = (va.y >> 16)          | (vb.y & 0xffff0000u);
        __syncthreads();

        f32x4 s[4];
        __builtin_amdgcn_s_setprio(1);
        #pragma unroll
        for (int kk = 0; kk < 4; ++kk) {
            s8v bk = *(const s8v*)(&Ks[kk * 16 + lr][hi * 8]);
            f32x4 z = {0.f,0.f,0.f,0.f};
            s[kk] = __builtin_amdgcn_mfma_f32_16x16x32_bf16(qf, bk, z, 0, 0, 0);
        }
        __builtin_amdgcn_s_setprio(0);
        if (kb + KT2 > LQ) {
            #pragma unroll
            for (int kk = 0; kk < 4; ++kk)
                if (kb + kk * 16 + lr >= LQ) {
                    s[kk][0] = -1e30f; s[kk][1] = -1e30f;
                    s[kk][2] = -1e30f; s[kk][3] = -1e30f;
                }
        }

        #pragma unroll
        for (int r = 0; r < 4; ++r) {
            float p0 = __expf(s[0][r]);
            float p1 = __expf(s[1][r]);
            float p2 = __expf(s[2][r]);
            float p3 = __expf(s[3][r]);
            lrun[r] += (p0 + p1) + (p2 + p3);
            int qr = hi * 4 + r;
            Ps[w][qr][lr]      = f2b(p0);
            Ps[w][qr][16 + lr] = f2b(p1);
            Ps[w][qr][32 + lr] = f2b(p2);
            Ps[w][qr][48 + lr] = f2b(p3);
        }

        s8v ap0  = *(const s8v*)(&Ps[w][lr][hi * 8]);
        s8v ap1  = *(const s8v*)(&Ps[w][lr][32 + hi * 8]);
        s8v bv00 = *(const s8v*)(&Vt32[lr][hi * 4]);
        s8v bv10 = *(const s8v*)(&Vt32[lr][16 + hi * 4]);
        s8v bv01 = *(const s8v*)(&Vt32[16 + lr][hi * 4]);
        s8v bv11 = *(const s8v*)(&Vt32[16 + lr][16 + hi * 4]);
        __builtin_amdgcn_s_setprio(1);
        o0 = __builtin_amdgcn_mfma_f32_16x16x32_bf16(ap0, bv00, o0, 0, 0, 0);
        o0 = __builtin_amdgcn_mfma_f32_16x16x32_bf16(ap1, bv10, o0, 0, 0, 0);
        o1 = __builtin_amdgcn_mfma_f32_16x16x32_bf16(ap0, bv01, o1, 0, 0, 0);
        o1 = __builtin_amdgcn_mfma_f32_16x16x32_bf16(ap1, bv11, o1, 0, 0, 0);
        __builtin_amdgcn_s_setprio(0);
    }

    #pragma unroll
    for (int r = 0; r < 4; ++r) {
        float ps = lrun[r];
        ps += __shfl_xor(ps, 1);
        ps += __shfl_xor(ps, 2);
        ps += __shfl_xor(ps, 4);
        ps += __shfl_xor(ps, 8);
        int q = q0 + hi * 4 + r;
        if (q < LQ) {
            float inv = 1.f / ps;
            u16* op = sa + (size_t)(b * LQ + q) * DD + h * HD;
            op[lr]      = f2b(o0[r] * inv);
            op[16 + lr] = f2b(o1[r] * inv);
        }
    }
}

// ------------------------------------------------ LN(x + bf16 y) -> out f32 [+ bf16(out+pos)]
__global__ __launch_bounds__(256)
void ln_kernel(const float* __restrict__ x, const u16* __restrict__ y,
               const float* __restrict__ g, const float* __restrict__ be,
               float* __restrict__ out, const float* __restrict__ pos,
               u16* __restrict__ bfout, int M)
{
    int wave = threadIdx.x >> 6;
    int lane = threadIdx.x & 63;
    int row = blockIdx.x * 4 + wave;
    if (row >= M) return;
    float4 xv = ((const float4*)(x + (size_t)row * DD))[lane];
    ushort4 yv = ((const ushort4*)(y + (size_t)row * DD))[lane];
    float v[4] = {xv.x + b2f(yv.x), xv.y + b2f(yv.y),
                  xv.z + b2f(yv.z), xv.w + b2f(yv.w)};
    float s = v[0] + v[1] + v[2] + v[3];
    float sq = v[0]*v[0] + v[1]*v[1] + v[2]*v[2] + v[3]*v[3];
    for (int o = 32; o; o >>= 1) {
        s += __shfl_xor(s, o);
        sq += __shfl_xor(sq, o);
    }
    float mean = s * (1.f / DD);
    float var = sq * (1.f / DD) - mean * mean;
    float r = rsqrtf(var + 1e-5f);
    float4 gv = ((const float4*)g)[lane];
    float4 bv = ((const float4*)be)[lane];
    float4 ov;
    ov.x = (v[0] - mean) * r * gv.x + bv.x;
    ov.y = (v[1] - mean) * r * gv.y + bv.y;
    ov.z = (v[2] - mean) * r * gv.z + bv.z;
    ov.w = (v[3] - mean) * r * gv.w + bv.w;
    ((float4*)(out + (size_t)row * DD))[lane] = ov;
    if (bfout) {
        float4 pv = make_float4(0.f, 0.f, 0.f, 0.f);
        if (pos) pv = ((const float4*)(pos + (size_t)row * DD))[lane];
        ushort4 bo;
        bo.x = f2b(ov.x + pv.x); bo.y = f2b(ov.y + pv.y);
        bo.z = f2b(ov.z + pv.z); bo.w = f2b(ov.w + pv.w);
        ((ushort4*)(bfout + (size_t)row * DD))[lane] = bo;
    }
}

// ------------------------------------------------ deformable sampling, 2-phase, u64 gathers
// offaw: (MP1, 384) f32.  Block: 2 bq, 256 thr.
// Phase A: 128 thr/bq compute the 128 (h,l,p) points once (idx in uint2 units).
// Phase B: thr = (jh, h, d4): 8 points x 4 corners = 32 uint2 gathers.
// Reduce the two jh halves via small LDS pass.
__global__ __launch_bounds__(256)
void sample_kernel(const float* __restrict__ offaw, const float* __restrict__ refp,
                   const u16* __restrict__ value, u16* __restrict__ out)
{
    __shared__ float2 sPW[2][128][4];   // (.x = idx bits (uint2 units), .y = weight)
    __shared__ float4 sRed[2][64];      // jh=1 partials
    int t = threadIdx.x;
    int sub = t >> 7;
    int bq = blockIdx.x * 2 + sub;
    int b = bq / LQ;

    {
        int pt = t & 127;
        int h = pt >> 4, j = pt & 15, l = j >> 2, p = j & 3;
        const float* row = offaw + (size_t)bq * 384;
        float lg = row[256 + h * 16 + j];
        float mx = lg;
        mx = fmaxf(mx, __shfl_xor(mx, 1));
        mx = fmaxf(mx, __shfl_xor(mx, 2));
        mx = fmaxf(mx, __shfl_xor(mx, 4));
        mx = fmaxf(mx, __shfl_xor(mx, 8));
        float e = __expf(lg - mx);
        float se = e;
        se += __shfl_xor(se, 1);
        se += __shfl_xor(se, 2);
        se += __shfl_xor(se, 4);
        se += __shfl_xor(se, 8);
        float aw = e / se;

        float ox = row[h * 32 + l * 8 + p * 2 + 0];
        float oy = row[h * 32 + l * 8 + p * 2 + 1];
        int Hc = c_H[l], Wc = c_W[l];
        float x = refp[(size_t)bq * 8 + l * 2 + 0] * Wc + ox - 0.5f;
        float y = refp[(size_t)bq * 8 + l * 2 + 1] * Hc + oy - 0.5f;
        float x0f = floorf(x), y0f = floorf(y);
        float lx = x - x0f, ly = y - y0f;
        int x0 = (int)x0f, y0 = (int)y0f;
        int vb = (b * S_TOT + c_base[l]) * 64;      // uint2 units per token = 64
        #pragma unroll
        for (int c = 0; c < 4; ++c) {
            int dy = c >> 1, dx = c & 1;
            int xi = x0 + dx, yi = y0 + dy;
            bool ok = (xi >= 0) & (xi < Wc) & (yi >= 0) & (yi < Hc);
            float wgt = (dy ? ly : 1.f - ly) * (dx ? lx : 1.f - lx) * aw;
            float2 pw;
            pw.x = __int_as_float(ok ? vb + (yi * Wc + xi) * 64 : 0);
            pw.y = ok ? wgt : 0.f;
            sPW[sub][pt][c] = pw;
        }
    }
    __syncthreads();

    // ---- phase B: 8-byte gathers
    int ts = t & 127;
    int jh = ts >> 6;          // 0 or 1 (which 8-point half)
    int s6 = ts & 63;          // (h, d4)
    int h = s6 >> 3, d4 = s6 & 7;
    {
        const uint2* v64 = (const uint2*)value;
        int lane = h * 8 + d4;
        float a0 = 0.f, a1 = 0.f, a2 = 0.f, a3 = 0.f;
        #pragma unroll
        for (int jj = 0; jj < 8; ++jj) {
            int pt = h * 16 + jh * 8 + jj;
            #pragma unroll
            for (int c = 0; c < 4; ++c) {
                float2 pw = sPW[sub][pt][c];
                uint2 g = v64[__float_as_int(pw.x) + lane];
                a0 += pw.y * __uint_as_float(g.x << 16);
                a1 += pw.y * __uint_as_float(g.x & 0xffff0000u);
                a2 += pw.y * __uint_as_float(g.y << 16);
                a3 += pw.y * __uint_as_float(g.y & 0xffff0000u);
            }
        }
        if (jh == 1) sRed[sub][s6] = make_float4(a0, a1, a2, a3);
        __syncthreads();
        if (jh == 0) {
            float4 p = sRed[sub][s6];
            a0 += p.x; a1 += p.y; a2 += p.z; a3 += p.w;
            uint2 o;
            o.x = pk2(a0, a1);
            o.y = pk2(a2, a3);
            *(uint2*)(out + (size_t)bq * DD + h * 32 + d4 * 4) = o;
        }
    }
}

// ---------------------------------------------------------------- launch
extern "C" void kernel_launch(void* const* d_in, const int* in_sizes, int n_in,
                              void* d_out, int out_size, void* d_ws, size_t ws_size,
                              hipStream_t stream)
{
    const float* tgt  = (const float*)d_in[0];
    const float* qpos = (const float*)d_in[1];
    const float* refp = (const float*)d_in[2];
    const float* src  = (const float*)d_in[3];
    const float* Wq  = (const float*)d_in[7];
    const float* pbq = (const float*)d_in[8];
    const float* Wk  = (const float*)d_in[9];
    const float* pbk = (const float*)d_in[10];
    const float* Wv  = (const float*)d_in[11];
    const float* pbv = (const float*)d_in[12];
    const float* Wo  = (const float*)d_in[13];
    const float* pbo = (const float*)d_in[14];
    const float* g2  = (const float*)d_in[15];
    const float* be2 = (const float*)d_in[16];
    const float* Woff = (const float*)d_in[17];
    const float* boff = (const float*)d_in[18];
    const float* Waw  = (const float*)d_in[19];
    const float* baw  = (const float*)d_in[20];
    const float* Wval = (const float*)d_in[21];
    const float* bval = (const float*)d_in[22];
    const float* Wout = (const float*)d_in[23];
    const float* bout = (const float*)d_in[24];
    const float* g1   = (const float*)d_in[25];
    const float* be1  = (const float*)d_in[26];
    const float* W1f  = (const float*)d_in[27];
    const float* b1f  = (const float*)d_in[28];
    const float* W2f  = (const float*)d_in[29];
    const float* b2f_ = (const float*)d_in[30];
    const float* g3   = (const float*)d_in[31];
    const float* be3  = (const float*)d_in[32];

    char* base = (char*)d_ws;
    size_t off = 0;
    auto alloc = [&](size_t bytes) -> void* {
        void* p = base + off;
        off = (off + bytes + 255) & ~(size_t)255;
        return p;
    };
    const size_t AB = (size_t)MP1 * DD * sizeof(u16);
    u16* B0  = (u16*)alloc(AB);                              // q_bf -> sa
    u16* B1  = (u16*)alloc(AB);                              // tgt_bf -> query_bf -> tgt3_bf
    u16* BQK = (u16*)alloc((size_t)MP1 * 512 * sizeof(u16)); // q|k
    u16* B4  = (u16*)alloc(AB);                              // vh -> sampout
    u16* TMPB= (u16*)alloc(AB);                              // bf16 tmp (pre-LN y)
    u16* FFH = (u16*)alloc((size_t)MP1 * DFF * sizeof(u16));
    u16* VAL = (u16*)alloc((size_t)MPV * DD * sizeof(u16));
    float* F0 = (float*)alloc((size_t)MP1 * 384 * sizeof(float));  // offaw
    float* F2 = (float*)alloc((size_t)MP1 * DD * sizeof(float));   // tgt2
    float* F3 = (float*)alloc((size_t)MP1 * DD * sizeof(float));   // tgt3
    u16* WTS = (u16*)alloc((size_t)WTS_TOT * sizeof(u16));
    float* bqk = (float*)alloc(512 * sizeof(float));
    float* boa = (float*)alloc(384 * sizeof(float));

    dim3 blk(256);

    prep_kernel<<<dim3(994), blk, 0, stream>>>(
        Wq, Wk, Wv, Wo, Wval, Wout, Woff, Waw, W1f, W2f,
        pbq, pbk, boff, baw, WTS, bqk, boa);

    const int MT = MP1 / 128;   // 113
    const dim3 gval(2, MPV / 64);         // value GEMM, 64x128 tile
    const dim3 g512b(8,  MT);             // N=512, BN=64
    const dim3 g256b(4,  MT);             // N=256, BN=64
    const dim3 g384b(6,  MT);             // N=384, BN=64
    const dim3 g1kb(16,  MT);             // N=1024, BN=64

    // ---- self-attention
    acvt2_kernel<<<dim3(MP1 * 32 / 256), blk, 0, stream>>>(tgt, qpos, B0, B1);
    mgemm<64,1,0><<<g512b, blk, 0, stream>>>(B0, WTS + OFF_QK, bqk, BQK, DD, 512, M1);
    mgemm<64,1,0><<<g256b, blk, 0, stream>>>(B1, WTS + OFF_V, pbv, B4, DD, DD, M1);
    mattn<<<dim3(BB * NH, (LQ + QT - 1) / QT), blk, 0, stream>>>(BQK, B4, B0);
    mgemm<64,1,0><<<g256b, blk, 0, stream>>>(B0, WTS + OFF_O, pbo, TMPB, DD, DD, M1);
    ln_kernel<<<dim3(M1 / 4), blk, 0, stream>>>(tgt, TMPB, g2, be2, F2, qpos, B1, M1);

    // ---- deformable cross-attention
    vgemm<<<gval, blk, 0, stream>>>(src, WTS + OFF_VAL, bval, VAL, MV);
    mgemm<64,0,0><<<g384b, blk, 0, stream>>>(B1, WTS + OFF_OA, boa, F0, DD, 384, M1);
    sample_kernel<<<dim3(M1 / 2), blk, 0, stream>>>(F0, refp, VAL, B4);
    mgemm<64,1,0><<<g256b, blk, 0, stream>>>(B4, WTS + OFF_OUT, bout, TMPB, DD, DD, M1);
    ln_kernel<<<dim3(M1 / 4), blk, 0, stream>>>(F2, TMPB, g1, be1, F3, nullptr, B1, M1);

    // ---- FFN
    mgemm<64,1,1><<<g1kb, blk, 0, stream>>>(B1, WTS + OFF_F1, b1f, FFH, DD, DFF, M1);
    mgemm<64,1,0><<<g256b, blk, 0, stream>>>(FFH, WTS + OFF_F2, b2f_, TMPB, DFF, DD, M1);
    ln_kernel<<<dim3(M1 / 4), blk, 0, stream>>>(F3, TMPB, g3, be3, (float*)d_out, nullptr, nullptr, M1);
}

// Round 18
// 313.762 us; speedup vs baseline: 1.0198x; 1.0198x over previous
//
#include <hip/hip_runtime.h>
#include <math.h>

#define DD 256
#define NH 8
#define HD 32
#define NL 4
#define NP 4
#define DFF 1024
#define BB 16
#define LQ 900
#define S_TOT 13294

#define M1   (BB * LQ)        // 14400
#define MP1  14464            // padded to 128
#define MV   (BB * S_TOT)     // 212704
#define MPV  212736           // padded to 128

typedef unsigned short u16;
typedef unsigned int   u32;
typedef __attribute__((ext_vector_type(8))) short s8v;   // 8 bf16 (4 VGPR)
typedef __attribute__((ext_vector_type(4))) float f32x4; // 4 f32 acc

// hard-coded level geometry (fixed constants of this problem)
__constant__ int c_H[NL]    = {100, 50, 25, 13};
__constant__ int c_W[NL]    = {100, 50, 25, 13};
__constant__ int c_base[NL] = {0, 10000, 12500, 13125};

__device__ __forceinline__ float b2f(u16 u) {
    return __uint_as_float(((u32)u) << 16);
}
__device__ __forceinline__ u16 f2b(float f) {
    u32 x = __float_as_uint(f);
    u32 r = x + 0x7fffu + ((x >> 16) & 1u);   // RNE
    return (u16)(r >> 16);
}
__device__ __forceinline__ u32 pk2(float a, float b) {
    return (u32)f2b(a) | ((u32)f2b(b) << 16);
}
// async global->LDS, 16B per lane; ldsbase must be wave-uniform
__device__ __forceinline__ void gload16(const u16* g, u16* ldsbase) {
    __builtin_amdgcn_global_load_lds(
        (const __attribute__((address_space(1))) unsigned int*)(const void*)g,
        (__attribute__((address_space(3))) unsigned int*)(void*)ldsbase,
        16, 0, 0);
}
// bijective XCD-aware swizzle (m204 form)
__device__ __forceinline__ int2 xcd_swizzle()
{
    int nwg  = gridDim.x * gridDim.y;
    int orig = blockIdx.y * gridDim.x + blockIdx.x;
    int q = nwg >> 3, r = nwg & 7;
    int xcd = orig & 7, pos = orig >> 3;
    int wg = (xcd < r ? xcd * (q + 1) : r * (q + 1) + (xcd - r) * q) + pos;
    int2 res;
    res.x = wg % gridDim.x;
    res.y = wg / gridDim.x;
    return res;
}

// WTS layout offsets (u16 units)
#define OFF_QK   0
#define OFF_V    131072
#define OFF_O    196608
#define OFF_VAL  262144
#define OFF_OUT  327680
#define OFF_OA   393216
#define OFF_F1   491520
#define OFF_F2   753664
#define WTS_TOT  1015808

// ------------------------------------------------ consolidated weight prep
__global__ __launch_bounds__(256)
void prep_kernel(const float* __restrict__ Wq, const float* __restrict__ Wk,
                 const float* __restrict__ Wv, const float* __restrict__ Wo,
                 const float* __restrict__ Wval, const float* __restrict__ Wout,
                 const float* __restrict__ Woff, const float* __restrict__ Waw,
                 const float* __restrict__ W1f, const float* __restrict__ W2f,
                 const float* __restrict__ pbq, const float* __restrict__ pbk,
                 const float* __restrict__ boff, const float* __restrict__ baw,
                 u16* __restrict__ WTS, float* __restrict__ bqk, float* __restrict__ boa)
{
    int t = blockIdx.x;
    if (t >= 992) {
        if (t == 992) {
            for (int i = threadIdx.x; i < 512; i += 256)
                bqk[i] = (i < 256) ? pbq[i] : pbk[i - 256];
        } else {
            for (int i = threadIdx.x; i < 384; i += 256)
                boa[i] = (i < 256) ? boff[i] : baw[i - 256];
        }
        return;
    }
    const float* src; u16* dst; int K, N, tt;
    if (t < 448) {
        int wsel = t >> 6; tt = t & 63;
        const float* srcs[7] = {Wq, Wk, Wv, Wo, Wval, Wout, Woff};
        const int   offs[7]  = {OFF_QK, OFF_QK + 65536, OFF_V, OFF_O, OFF_VAL, OFF_OUT, OFF_OA};
        src = srcs[wsel]; dst = WTS + offs[wsel]; K = 256; N = 256;
    } else if (t < 480) {
        tt = t - 448; src = Waw; dst = WTS + OFF_OA + 65536; K = 256; N = 128;
    } else if (t < 736) {
        tt = t - 480; src = W1f; dst = WTS + OFF_F1; K = 256; N = 1024;
    } else {
        tt = t - 736; src = W2f; dst = WTS + OFF_F2; K = 1024; N = 256;
    }
    int nt = N / 32;
    int n0 = (tt % nt) * 32, k0 = (tt / nt) * 32;

    __shared__ float tb[32][33];
    int tx = threadIdx.x & 31, ty = threadIdx.x >> 5;
    #pragma unroll
    for (int i = 0; i < 4; ++i) {
        int k = ty + i * 8;
        tb[k][tx] = src[(size_t)(k0 + k) * N + n0 + tx];
    }
    __syncthreads();
    #pragma unroll
    for (int i = 0; i < 4; ++i) {
        int n = ty + i * 8;
        dst[(size_t)(n0 + n) * K + k0 + tx] = f2b(tb[tx][n]);
    }
}

// ------------------------------------------------ dual activation cvt
__global__ __launch_bounds__(256)
void acvt2_kernel(const float* __restrict__ tgt, const float* __restrict__ qpos,
                  u16* __restrict__ B0, u16* __restrict__ B1)
{
    int i8 = blockIdx.x * 256 + threadIdx.x;
    int row = i8 >> 5;
    uint4 o0, o1;
    if (row < M1) {
        const float4* tp = (const float4*)(tgt + (size_t)i8 * 8);
        const float4* pp = (const float4*)(qpos + (size_t)i8 * 8);
        float4 t0 = tp[0], t1 = tp[1], p0 = pp[0], p1 = pp[1];
        o1.x = pk2(t0.x, t0.y); o1.y = pk2(t0.z, t0.w);
        o1.z = pk2(t1.x, t1.y); o1.w = pk2(t1.z, t1.w);
        o0.x = pk2(t0.x + p0.x, t0.y + p0.y); o0.y = pk2(t0.z + p0.z, t0.w + p0.w);
        o0.z = pk2(t1.x + p1.x, t1.y + p1.y); o0.w = pk2(t1.z + p1.z, t1.w + p1.w);
    } else {
        o0.x = o0.y = o0.z = o0.w = 0;
        o1 = o0;
    }
    ((uint4*)B0)[i8] = o0;
    ((uint4*)B1)[i8] = o1;
}

// ------------------------------------------------ bf16 MFMA GEMM, 2-phase dbuf + XCD swizzle
template<int BNT, int OUTBF, int RELU>
__global__ __launch_bounds__(256)
void mgemm(const u16* __restrict__ A, const u16* __restrict__ Bt,
           const float* __restrict__ bias, void* __restrict__ Cv,
           int K, int N, int Mreal)
{
    constexpr int MF = (BNT == 128) ? 4 : 2;
    __shared__ u16 Asu[2][128 * 32];
    __shared__ u16 Bsu[2][BNT * 32];

    int2 sw = xcd_swizzle();
    int tid = threadIdx.x;
    int w = tid >> 6, l = tid & 63;
    int mbase = (BNT == 128) ? (w >> 1) * 64 : w * 32;
    int nbase = (BNT == 128) ? (w & 1) * 64 : 0;
    long m0 = (long)sw.y * 128;
    int n0 = sw.x * BNT;

    f32x4 acc[MF][4];
    #pragma unroll
    for (int i = 0; i < MF; ++i)
        #pragma unroll
        for (int j = 0; j < 4; ++j) {
            acc[i][j][0] = 0.f; acc[i][j][1] = 0.f;
            acc[i][j][2] = 0.f; acc[i][j][3] = 0.f;
        }

    int lr = l & 15, lk = (l >> 4) * 8;
    int srow = l >> 2;
    int scol = (l & 3) * 8;

    auto stage = [&](int buf, int k0) {
        if (BNT == 128) {
            #pragma unroll
            for (int j = 0; j < 2; ++j) {
                int row = w * 32 + j * 16;
                gload16(Bt + (size_t)(n0 + row + srow) * K + k0 + scol, &Bsu[buf][row * 32]);
            }
        } else {
            int row = w * 16;
            gload16(Bt + (size_t)(n0 + row + srow) * K + k0 + scol, &Bsu[buf][row * 32]);
        }
        #pragma unroll
        for (int j = 0; j < 2; ++j) {
            int row = w * 32 + j * 16;
            gload16(A + (m0 + row + srow) * (long)K + k0 + scol, &Asu[buf][row * 32]);
        }
    };

    int nsteps = K >> 5;
    stage(0, 0);
    __syncthreads();

    int cur = 0;
    for (int s = 0; s < nsteps; ++s) {
        if (s + 1 < nsteps) stage(cur ^ 1, (s + 1) * 32);
        s8v af[MF], bf[4];
        #pragma unroll
        for (int mi = 0; mi < MF; ++mi)
            af[mi] = *(const s8v*)(Asu[cur] + (mbase + mi * 16 + lr) * 32 + lk);
        #pragma unroll
        for (int nj = 0; nj < 4; ++nj)
            bf[nj] = *(const s8v*)(Bsu[cur] + (nbase + nj * 16 + lr) * 32 + lk);
        #pragma unroll
        for (int mi = 0; mi < MF; ++mi)
            #pragma unroll
            for (int nj = 0; nj < 4; ++nj)
                acc[mi][nj] = __builtin_amdgcn_mfma_f32_16x16x32_bf16(
                    af[mi], bf[nj], acc[mi][nj], 0, 0, 0);
        __syncthreads();
        cur ^= 1;
    }

    int lq = l >> 4;
    #pragma unroll
    for (int nj = 0; nj < 4; ++nj) {
        int col = n0 + nbase + nj * 16 + lr;
        float bv = bias[col];
        #pragma unroll
        for (int mi = 0; mi < MF; ++mi) {
            #pragma unroll
            for (int r = 0; r < 4; ++r) {
                long row = m0 + mbase + mi * 16 + lq * 4 + r;
                float v = acc[mi][nj][r] + bv;
                if (RELU) v = fmaxf(v, 0.f);
                if (OUTBF) ((u16*)Cv)[row * N + col] = f2b(v);
                else       ((float*)Cv)[row * N + col] = v;
            }
        }
    }
}

// ------------------------------------------------ value GEMM: 64x128 tile + XCD swizzle
__global__ __launch_bounds__(256)
void vgemm(const float* __restrict__ A, const u16* __restrict__ Bt,
           const float* __restrict__ bias, u16* __restrict__ C, int Mreal)
{
    const int K = 256, N = 256;
    __shared__ u16 Asu[64 * 32];
    __shared__ u16 Bsu[128 * 32];

    int2 sw = xcd_swizzle();
    int tid = threadIdx.x;
    int w = tid >> 6, l = tid & 63;
    int wr = w >> 1, wc = w & 1;
    long m0 = (long)sw.y * 64;
    int n0 = sw.x * 128;

    f32x4 acc[2][4];
    #pragma unroll
    for (int i = 0; i < 2; ++i)
        #pragma unroll
        for (int j = 0; j < 4; ++j) {
            acc[i][j][0] = 0.f; acc[i][j][1] = 0.f;
            acc[i][j][2] = 0.f; acc[i][j][3] = 0.f;
        }

    int lr = l & 15, lk = (l >> 4) * 8;
    int srow = l >> 2, scol = (l & 3) * 8;

    for (int k0 = 0; k0 < K; k0 += 32) {
        #pragma unroll
        for (int j = 0; j < 2; ++j) {
            int row = w * 32 + j * 16;
            gload16(Bt + (size_t)(n0 + row + srow) * K + k0 + scol, &Bsu[row * 32]);
        }
        int c = tid;
        #pragma unroll
        for (int it = 0; it < 2; ++it) {
            int row = c >> 3, col = (c & 7) * 4;
            long gr = m0 + row;
            if (gr >= Mreal) gr = Mreal - 1;
            float4 v = *(const float4*)(A + gr * K + k0 + col);
            ushort4 o;
            o.x = f2b(v.x); o.y = f2b(v.y); o.z = f2b(v.z); o.w = f2b(v.w);
            ((ushort4*)Asu)[c] = o;
            c += 256;
        }
        __syncthreads();
        s8v af[2], bf[4];
        #pragma unroll
        for (int mi = 0; mi < 2; ++mi)
            af[mi] = *(const s8v*)(Asu + (wr * 32 + mi * 16 + lr) * 32 + lk);
        #pragma unroll
        for (int nj = 0; nj < 4; ++nj)
            bf[nj] = *(const s8v*)(Bsu + (wc * 64 + nj * 16 + lr) * 32 + lk);
        #pragma unroll
        for (int mi = 0; mi < 2; ++mi)
            #pragma unroll
            for (int nj = 0; nj < 4; ++nj)
                acc[mi][nj] = __builtin_amdgcn_mfma_f32_16x16x32_bf16(
                    af[mi], bf[nj], acc[mi][nj], 0, 0, 0);
        __syncthreads();
    }

    int lq = l >> 4;
    #pragma unroll
    for (int nj = 0; nj < 4; ++nj) {
        int col = n0 + wc * 64 + nj * 16 + lr;
        float bv = bias[col];
        #pragma unroll
        for (int mi = 0; mi < 2; ++mi) {
            #pragma unroll
            for (int r = 0; r < 4; ++r) {
                long row = m0 + wr * 32 + mi * 16 + lq * 4 + r;
                C[row * N + col] = f2b(acc[mi][nj][r] + bv);
            }
        }
    }
}

// ------------------------------------------------ MFMA flash self-attention, KT=64
#define QT 64
#define KT2 64
#define KSP 48
#define VSP 40
#define PSP 72
__global__ __launch_bounds__(256)
void mattn(const u16* __restrict__ qk, const u16* __restrict__ vh,
           u16* __restrict__ sa)
{
    __shared__ u16 Ks[KT2][KSP];
    __shared__ u32 Vt32[32][VSP];
    __shared__ u16 Ps[4][16][PSP];

    int tid = threadIdx.x;
    int w = tid >> 6, l = tid & 63;
    int lr = l & 15, hi = l >> 4;
    int b = blockIdx.x >> 3, h = blockIdx.x & 7;
    int q0 = blockIdx.y * QT + w * 16;

    s8v qf;
    {
        s8v raw = *(const s8v*)(qk + ((size_t)(b * LQ + q0 + lr) * 512) + h * HD + hi * 8);
        #pragma unroll
        for (int j = 0; j < 8; ++j)
            raw[j] = (short)f2b(b2f((u16)raw[j]) * 0.17677669529663687f);
        qf = raw;
    }

    f32x4 o0 = {0.f,0.f,0.f,0.f}, o1 = {0.f,0.f,0.f,0.f};
    float lrun[4] = {0.f,0.f,0.f,0.f};

    const u16* kbase = qk + (size_t)b * LQ * 512 + 256 + h * HD;
    const u16* vbase = vh + (size_t)b * LQ * 256 + h * HD;

    int krow = tid >> 2, kc8 = (tid & 3) * 8;
    int k2 = tid & 31, d0 = (tid >> 5) * 4;

    for (int kb = 0; kb < LQ; kb += KT2) {
        int gk = kb + krow;        if (gk >= LQ) gk = LQ - 1;
        int gv0 = kb + 2 * k2;     if (gv0 >= LQ) gv0 = LQ - 1;
        int gv1 = kb + 2 * k2 + 1; if (gv1 >= LQ) gv1 = LQ - 1;
        uint4 kv = *(const uint4*)(kbase + (size_t)gk * 512 + kc8);
        uint2 va = *(const uint2*)(vbase + (size_t)gv0 * 256 + d0);
        uint2 vb = *(const uint2*)(vbase + (size_t)gv1 * 256 + d0);
        __syncthreads();
        *(uint4*)(&Ks[krow][kc8]) = kv;
        Vt32[d0 + 0][k2] = (va.x & 0xffffu)      | (vb.x << 16);
        Vt32[d0 + 1][k2] = (va.x >> 16)          | (vb.x & 0xffff0000u);
        Vt32[d0 + 2][k2] = (va.y & 0xffffu)      | (vb.y << 16);
        Vt32[d0 + 3][k2] = (va.y >> 16)          | (vb.y & 0xffff0000u);
        __syncthreads();

        f32x4 s[4];
        #pragma unroll
        for (int kk = 0; kk < 4; ++kk) {
            s8v bk = *(const s8v*)(&Ks[kk * 16 + lr][hi * 8]);
            f32x4 z = {0.f,0.f,0.f,0.f};
            s[kk] = __builtin_amdgcn_mfma_f32_16x16x32_bf16(qf, bk, z, 0, 0, 0);
        }
        if (kb + KT2 > LQ) {
            #pragma unroll
            for (int kk = 0; kk < 4; ++kk)
                if (kb + kk * 16 + lr >= LQ) {
                    s[kk][0] = -1e30f; s[kk][1] = -1e30f;
                    s[kk][2] = -1e30f; s[kk][3] = -1e30f;
                }
        }

        #pragma unroll
        for (int r = 0; r < 4; ++r) {
            float p0 = __expf(s[0][r]);
            float p1 = __expf(s[1][r]);
            float p2 = __expf(s[2][r]);
            float p3 = __expf(s[3][r]);
            lrun[r] += (p0 + p1) + (p2 + p3);
            int qr = hi * 4 + r;
            Ps[w][qr][lr]      = f2b(p0);
            Ps[w][qr][16 + lr] = f2b(p1);
            Ps[w][qr][32 + lr] = f2b(p2);
            Ps[w][qr][48 + lr] = f2b(p3);
        }

        s8v ap0  = *(const s8v*)(&Ps[w][lr][hi * 8]);
        s8v ap1  = *(const s8v*)(&Ps[w][lr][32 + hi * 8]);
        s8v bv00 = *(const s8v*)(&Vt32[lr][hi * 4]);
        s8v bv10 = *(const s8v*)(&Vt32[lr][16 + hi * 4]);
        s8v bv01 = *(const s8v*)(&Vt32[16 + lr][hi * 4]);
        s8v bv11 = *(const s8v*)(&Vt32[16 + lr][16 + hi * 4]);
        o0 = __builtin_amdgcn_mfma_f32_16x16x32_bf16(ap0, bv00, o0, 0, 0, 0);
        o0 = __builtin_amdgcn_mfma_f32_16x16x32_bf16(ap1, bv10, o0, 0, 0, 0);
        o1 = __builtin_amdgcn_mfma_f32_16x16x32_bf16(ap0, bv01, o1, 0, 0, 0);
        o1 = __builtin_amdgcn_mfma_f32_16x16x32_bf16(ap1, bv11, o1, 0, 0, 0);
    }

    #pragma unroll
    for (int r = 0; r < 4; ++r) {
        float ps = lrun[r];
        ps += __shfl_xor(ps, 1);
        ps += __shfl_xor(ps, 2);
        ps += __shfl_xor(ps, 4);
        ps += __shfl_xor(ps, 8);
        int q = q0 + hi * 4 + r;
        if (q < LQ) {
            float inv = 1.f / ps;
            u16* op = sa + (size_t)(b * LQ + q) * DD + h * HD;
            op[lr]      = f2b(o0[r] * inv);
            op[16 + lr] = f2b(o1[r] * inv);
        }
    }
}

// ------------------------------------------------ LN(x + bf16 y) -> out f32 [+ bf16(out+pos)]
__global__ __launch_bounds__(256)
void ln_kernel(const float* __restrict__ x, const u16* __restrict__ y,
               const float* __restrict__ g, const float* __restrict__ be,
               float* __restrict__ out, const float* __restrict__ pos,
               u16* __restrict__ bfout, int M)
{
    int wave = threadIdx.x >> 6;
    int lane = threadIdx.x & 63;
    int row = blockIdx.x * 4 + wave;
    if (row >= M) return;
    float4 xv = ((const float4*)(x + (size_t)row * DD))[lane];
    ushort4 yv = ((const ushort4*)(y + (size_t)row * DD))[lane];
    float v[4] = {xv.x + b2f(yv.x), xv.y + b2f(yv.y),
                  xv.z + b2f(yv.z), xv.w + b2f(yv.w)};
    float s = v[0] + v[1] + v[2] + v[3];
    float sq = v[0]*v[0] + v[1]*v[1] + v[2]*v[2] + v[3]*v[3];
    for (int o = 32; o; o >>= 1) {
        s += __shfl_xor(s, o);
        sq += __shfl_xor(sq, o);
    }
    float mean = s * (1.f / DD);
    float var = sq * (1.f / DD) - mean * mean;
    float r = rsqrtf(var + 1e-5f);
    float4 gv = ((const float4*)g)[lane];
    float4 bv = ((const float4*)be)[lane];
    float4 ov;
    ov.x = (v[0] - mean) * r * gv.x + bv.x;
    ov.y = (v[1] - mean) * r * gv.y + bv.y;
    ov.z = (v[2] - mean) * r * gv.z + bv.z;
    ov.w = (v[3] - mean) * r * gv.w + bv.w;
    ((float4*)(out + (size_t)row * DD))[lane] = ov;
    if (bfout) {
        float4 pv = make_float4(0.f, 0.f, 0.f, 0.f);
        if (pos) pv = ((const float4*)(pos + (size_t)row * DD))[lane];
        ushort4 bo;
        bo.x = f2b(ov.x + pv.x); bo.y = f2b(ov.y + pv.y);
        bo.z = f2b(ov.z + pv.z); bo.w = f2b(ov.w + pv.w);
        ((ushort4*)(bfout + (size_t)row * DD))[lane] = bo;
    }
}

// ------------------------------------------------ deformable sampling, 2-phase
__global__ __launch_bounds__(256)
void sample_kernel(const float* __restrict__ offaw, const float* __restrict__ refp,
                   const u16* __restrict__ value, u16* __restrict__ out)
{
    __shared__ float2 sPW[2][128][4];   // (.x = idx bits (u32 units), .y = weight)
    int t = threadIdx.x;
    int sub = t >> 7;
    int bq = blockIdx.x * 2 + sub;
    int b = bq / LQ;

    {
        int pt = t & 127;
        int h = pt >> 4, j = pt & 15, l = j >> 2, p = j & 3;
        const float* row = offaw + (size_t)bq * 384;
        float lg = row[256 + h * 16 + j];
        float mx = lg;
        mx = fmaxf(mx, __shfl_xor(mx, 1));
        mx = fmaxf(mx, __shfl_xor(mx, 2));
        mx = fmaxf(mx, __shfl_xor(mx, 4));
        mx = fmaxf(mx, __shfl_xor(mx, 8));
        float e = __expf(lg - mx);
        float se = e;
        se += __shfl_xor(se, 1);
        se += __shfl_xor(se, 2);
        se += __shfl_xor(se, 4);
        se += __shfl_xor(se, 8);
        float aw = e / se;

        float ox = row[h * 32 + l * 8 + p * 2 + 0];
        float oy = row[h * 32 + l * 8 + p * 2 + 1];
        int Hc = c_H[l], Wc = c_W[l];
        float x = refp[(size_t)bq * 8 + l * 2 + 0] * Wc + ox - 0.5f;
        float y = refp[(size_t)bq * 8 + l * 2 + 1] * Hc + oy - 0.5f;
        float x0f = floorf(x), y0f = floorf(y);
        float lx = x - x0f, ly = y - y0f;
        int x0 = (int)x0f, y0 = (int)y0f;
        int vb = (b * S_TOT + c_base[l]) * 128;     // u32 units per token = 128
        #pragma unroll
        for (int c = 0; c < 4; ++c) {
            int dy = c >> 1, dx = c & 1;
            int xi = x0 + dx, yi = y0 + dy;
            bool ok = (xi >= 0) & (xi < Wc) & (yi >= 0) & (yi < Hc);
            float wgt = (dy ? ly : 1.f - ly) * (dx ? lx : 1.f - lx) * aw;
            float2 pw;
            pw.x = __int_as_float(ok ? vb + (yi * Wc + xi) * 128 : 0);
            pw.y = ok ? wgt : 0.f;
            sPW[sub][pt][c] = pw;
        }
    }
    __syncthreads();

    {
        int s = t & 127;
        int h = s >> 4, d2 = s & 15;
        const u32* v32 = (const u32*)value;
        int lane = h * 16 + d2;
        float a0 = 0.f, a1 = 0.f;
        #pragma unroll
        for (int j = 0; j < 16; ++j) {
            #pragma unroll
            for (int c = 0; c < 4; ++c) {
                float2 pw = sPW[sub][h * 16 + j][c];
                u32 pv = v32[__float_as_int(pw.x) + lane];
                a0 += pw.y * __uint_as_float(pv << 16);
                a1 += pw.y * __uint_as_float(pv & 0xffff0000u);
            }
        }
        *(u32*)(out + (size_t)bq * DD + h * 32 + d2 * 2) = pk2(a0, a1);
    }
}

// ---------------------------------------------------------------- launch
extern "C" void kernel_launch(void* const* d_in, const int* in_sizes, int n_in,
                              void* d_out, int out_size, void* d_ws, size_t ws_size,
                              hipStream_t stream)
{
    const float* tgt  = (const float*)d_in[0];
    const float* qpos = (const float*)d_in[1];
    const float* refp = (const float*)d_in[2];
    const float* src  = (const float*)d_in[3];
    const float* Wq  = (const float*)d_in[7];
    const float* pbq = (const float*)d_in[8];
    const float* Wk  = (const float*)d_in[9];
    const float* pbk = (const float*)d_in[10];
    const float* Wv  = (const float*)d_in[11];
    const float* pbv = (const float*)d_in[12];
    const float* Wo  = (const float*)d_in[13];
    const float* pbo = (const float*)d_in[14];
    const float* g2  = (const float*)d_in[15];
    const float* be2 = (const float*)d_in[16];
    const float* Woff = (const float*)d_in[17];
    const float* boff = (const float*)d_in[18];
    const float* Waw  = (const float*)d_in[19];
    const float* baw  = (const float*)d_in[20];
    const float* Wval = (const float*)d_in[21];
    const float* bval = (const float*)d_in[22];
    const float* Wout = (const float*)d_in[23];
    const float* bout = (const float*)d_in[24];
    const float* g1   = (const float*)d_in[25];
    const float* be1  = (const float*)d_in[26];
    const float* W1f  = (const float*)d_in[27];
    const float* b1f  = (const float*)d_in[28];
    const float* W2f  = (const float*)d_in[29];
    const float* b2f_ = (const float*)d_in[30];
    const float* g3   = (const float*)d_in[31];
    const float* be3  = (const float*)d_in[32];

    char* base = (char*)d_ws;
    size_t off = 0;
    auto alloc = [&](size_t bytes) -> void* {
        void* p = base + off;
        off = (off + bytes + 255) & ~(size_t)255;
        return p;
    };
    const size_t AB = (size_t)MP1 * DD * sizeof(u16);
    u16* B0  = (u16*)alloc(AB);                              // q_bf -> sa
    u16* B1  = (u16*)alloc(AB);                              // tgt_bf -> query_bf -> tgt3_bf
    u16* BQK = (u16*)alloc((size_t)MP1 * 512 * sizeof(u16)); // q|k
    u16* B4  = (u16*)alloc(AB);                              // vh -> sampout
    u16* TMPB= (u16*)alloc(AB);                              // bf16 tmp (pre-LN y)
    u16* FFH = (u16*)alloc((size_t)MP1 * DFF * sizeof(u16));
    u16* VAL = (u16*)alloc((size_t)MPV * DD * sizeof(u16));
    float* F0 = (float*)alloc((size_t)MP1 * 384 * sizeof(float));  // offaw
    float* F2 = (float*)alloc((size_t)MP1 * DD * sizeof(float));   // tgt2
    float* F3 = (float*)alloc((size_t)MP1 * DD * sizeof(float));   // tgt3
    u16* WTS = (u16*)alloc((size_t)WTS_TOT * sizeof(u16));
    float* bqk = (float*)alloc(512 * sizeof(float));
    float* boa = (float*)alloc(384 * sizeof(float));

    dim3 blk(256);

    prep_kernel<<<dim3(994), blk, 0, stream>>>(
        Wq, Wk, Wv, Wo, Wval, Wout, Woff, Waw, W1f, W2f,
        pbq, pbk, boff, baw, WTS, bqk, boa);

    const int MT = MP1 / 128;   // 113
    const dim3 gval(2, MPV / 64);         // value GEMM, 64x128 tile
    const dim3 g512b(8,  MT);             // N=512, BN=64
    const dim3 g256b(4,  MT);             // N=256, BN=64
    const dim3 g384b(6,  MT);             // N=384, BN=64
    const dim3 g1kb(16,  MT);             // N=1024, BN=64

    // ---- self-attention
    acvt2_kernel<<<dim3(MP1 * 32 / 256), blk, 0, stream>>>(tgt, qpos, B0, B1);
    mgemm<64,1,0><<<g512b, blk, 0, stream>>>(B0, WTS + OFF_QK, bqk, BQK, DD, 512, M1);
    mgemm<64,1,0><<<g256b, blk, 0, stream>>>(B1, WTS + OFF_V, pbv, B4, DD, DD, M1);
    mattn<<<dim3(BB * NH, (LQ + QT - 1) / QT), blk, 0, stream>>>(BQK, B4, B0);
    mgemm<64,1,0><<<g256b, blk, 0, stream>>>(B0, WTS + OFF_O, pbo, TMPB, DD, DD, M1);
    ln_kernel<<<dim3(M1 / 4), blk, 0, stream>>>(tgt, TMPB, g2, be2, F2, qpos, B1, M1);

    // ---- deformable cross-attention
    vgemm<<<gval, blk, 0, stream>>>(src, WTS + OFF_VAL, bval, VAL, MV);
    mgemm<64,0,0><<<g384b, blk, 0, stream>>>(B1, WTS + OFF_OA, boa, F0, DD, 384, M1);
    sample_kernel<<<dim3(M1 / 2), blk, 0, stream>>>(F0, refp, VAL, B4);
    mgemm<64,1,0><<<g256b, blk, 0, stream>>>(B4, WTS + OFF_OUT, bout, TMPB, DD, DD, M1);
    ln_kernel<<<dim3(M1 / 4), blk, 0, stream>>>(F2, TMPB, g1, be1, F3, nullptr, B1, M1);

    // ---- FFN
    mgemm<64,1,1><<<g1kb, blk, 0, stream>>>(B1, WTS + OFF_F1, b1f, FFH, DD, DFF, M1);
    mgemm<64,1,0><<<g256b, blk, 0, stream>>>(FFH, WTS + OFF_F2, b2f_, TMPB, DFF, DD, M1);
    ln_kernel<<<dim3(M1 / 4), blk, 0, stream>>>(F3, TMPB, g3, be3, (float*)d_out, nullptr, nullptr, M1);
}